// Round 1
// baseline (241.447 us; speedup 1.0000x reference)
//
#include <hip/hip_runtime.h>

typedef unsigned int u32;
typedef unsigned short u16;
typedef __attribute__((ext_vector_type(4))) float f32x4;
typedef __attribute__((ext_vector_type(8))) __bf16 bf16x8;
typedef __attribute__((ext_vector_type(4))) u32 u32x4;

// fp32 -> bf16 with round-to-nearest-even
__device__ __forceinline__ u32 f2bf(float f) {
    u32 u = __builtin_bit_cast(u32, f);
    return (u + 0x7fffu + ((u >> 16) & 1u)) >> 16;
}
__device__ __forceinline__ u32 pk2(float lo, float hi) {
    return f2bf(lo) | (f2bf(hi) << 16);
}
__device__ __forceinline__ float bf2f(u16 v) {
    return __builtin_bit_cast(float, ((u32)v) << 16);
}

// LDS tile: 16 rows x 136 bf16 (stride 136 => +8 pad: bank-balanced for both
// row-major b128 writes and A-fragment b128 reads). Union keeps u16 scatter
// writes and u32x4 vector reads alias-safe under TBAA.
union LdsTile {
    u16 h[16 * 136];
    u32x4 v[16 * 17];   // 17 u32x4 per row
};

// ---------------------------------------------------------------------------
// Kernel 1: agent_proj[a][c] = x_agent[a] . W1[128:256][c] + b1[c]   (bf16)
// M=50000, K=128, N=128. One wave per 16-agent tile, W1-high fragments in
// 128 VGPRs, mfma_f32_16x16x32_bf16.
// ---------------------------------------------------------------------------
__global__ __launch_bounds__(256, 2)
void agent_proj_kernel(const float* __restrict__ x_agent,
                       const float* __restrict__ W1,
                       const float* __restrict__ b1,
                       u16* __restrict__ proj, int n_agents)
{
    __shared__ LdsTile Abuf[4];
    const int wid = threadIdx.x >> 6;
    const int l   = threadIdx.x & 63;
    const int n   = l & 15;        // MFMA "n"/"m" lane index
    const int q   = l >> 4;        // quad

    // B fragments: B[k][col], k = kk*32 + q*8 + j (rows 128..255 of W1)
    u32x4 wf[8][4];
#pragma unroll
    for (int nt = 0; nt < 8; ++nt) {
        const int col = nt * 16 + n;
#pragma unroll
        for (int kk = 0; kk < 4; ++kk) {
            u32x4 w;
#pragma unroll
            for (int jp = 0; jp < 4; ++jp) {
                const int k = 128 + kk * 32 + q * 8 + jp * 2;
                w[jp] = pk2(W1[(size_t)k * 128 + col], W1[(size_t)(k + 1) * 128 + col]);
            }
            wf[nt][kk] = w;
        }
    }
    float b1v[8];
#pragma unroll
    for (int nt = 0; nt < 8; ++nt) b1v[nt] = b1[nt * 16 + n];

    const int n_tiles = n_agents >> 4;
    const int gw = blockIdx.x * 4 + wid;
    const int stride = gridDim.x * 4;
    const f32x4 zero = {0.f, 0.f, 0.f, 0.f};

    for (int t = gw; t < n_tiles; t += stride) {
        const int a0 = t * 16;
        // stage x_agent rows -> bf16 LDS tile (each quad q does rows it*4+q)
#pragma unroll
        for (int it = 0; it < 4; ++it) {
            const int m = it * 4 + q;
            const float* bp = x_agent + (size_t)(a0 + m) * 128 + n * 8;
            const float4 v0 = *(const float4*)bp;
            const float4 v1 = *(const float4*)(bp + 4);
            u32x4 pkv;
            pkv[0] = pk2(v0.x, v0.y); pkv[1] = pk2(v0.z, v0.w);
            pkv[2] = pk2(v1.x, v1.y); pkv[3] = pk2(v1.z, v1.w);
            Abuf[wid].v[m * 17 + n] = pkv;
        }
        f32x4 acc[8];
#pragma unroll
        for (int nt = 0; nt < 8; ++nt) acc[nt] = zero;
#pragma unroll
        for (int kk = 0; kk < 4; ++kk) {
            const u32x4 a = Abuf[wid].v[n * 17 + kk * 4 + q];  // A[m=n][k..k+7]
#pragma unroll
            for (int nt = 0; nt < 8; ++nt)
                acc[nt] = __builtin_amdgcn_mfma_f32_16x16x32_bf16(
                    __builtin_bit_cast(bf16x8, a),
                    __builtin_bit_cast(bf16x8, wf[nt][kk]), acc[nt], 0, 0, 0);
        }
        // C/D: row m = q*4+r, col = nt*16+n ; store bf16 (pre-relu partial + b1)
#pragma unroll
        for (int nt = 0; nt < 8; ++nt) {
#pragma unroll
            for (int r = 0; r < 4; ++r) {
                const int m = q * 4 + r;
                proj[(size_t)(a0 + m) * 128 + nt * 16 + n] =
                    (u16)f2bf(acc[nt][r] + b1v[nt]);
            }
        }
    }
}

// ---------------------------------------------------------------------------
// Kernel 2: per-edge MLP. One wave per 16-edge tile, no barriers.
// hidden = relu(x_nbr[src].W1[:128] + proj[dst]); score = hidden.W2 + b2
// scatter to out[dst][slot*8 + o].
// ---------------------------------------------------------------------------
__global__ __launch_bounds__(256, 2)
void edge_mlp_kernel(const float* __restrict__ x_nbr,
                     const float* __restrict__ W1,
                     const float* __restrict__ W2,
                     const float* __restrict__ b2,
                     const u16* __restrict__ proj,
                     const int* __restrict__ edge_src,
                     const int* __restrict__ edge_dst,
                     const int* __restrict__ edge_slot,
                     float* __restrict__ out, int n_tiles)
{
    __shared__ LdsTile Abuf[4];
    __shared__ LdsTile Hbuf[4];
    const int wid = threadIdx.x >> 6;
    const int l   = threadIdx.x & 63;
    const int n   = l & 15;
    const int q   = l >> 4;

    // W1 low-half fragments (k = 0..127) in registers: 128 VGPRs
    u32x4 wf[8][4];
#pragma unroll
    for (int nt = 0; nt < 8; ++nt) {
        const int col = nt * 16 + n;
#pragma unroll
        for (int kk = 0; kk < 4; ++kk) {
            u32x4 w;
#pragma unroll
            for (int jp = 0; jp < 4; ++jp) {
                const int k = kk * 32 + q * 8 + jp * 2;
                w[jp] = pk2(W1[(size_t)k * 128 + col], W1[(size_t)(k + 1) * 128 + col]);
            }
            wf[nt][kk] = w;
        }
    }
    // W2 fragments (N padded 8->16 with zeros)
    u32x4 w2f[4];
#pragma unroll
    for (int kk = 0; kk < 4; ++kk) {
        u32x4 w;
#pragma unroll
        for (int jp = 0; jp < 4; ++jp) {
            const int k = kk * 32 + q * 8 + jp * 2;
            const float f0 = (n < 8) ? W2[(size_t)k * 8 + n] : 0.f;
            const float f1 = (n < 8) ? W2[(size_t)(k + 1) * 8 + n] : 0.f;
            w[jp] = pk2(f0, f1);
        }
        w2f[kk] = w;
    }
    const float b2v = (n < 8) ? b2[n] : 0.f;

    const int gw = blockIdx.x * 4 + wid;
    const int stride = gridDim.x * 4;
    const f32x4 zero = {0.f, 0.f, 0.f, 0.f};

    for (int t = gw; t < n_tiles; t += stride) {
        const int eb = t * 16;
        int src_l = 0, dst_l = 0, slot_l = 0;
        if (l < 16) {
            src_l  = edge_src[eb + l];
            dst_l  = edge_dst[eb + l];
            slot_l = edge_slot[eb + l];
        }
        // stage x_nbr[src] rows -> bf16 tile
#pragma unroll
        for (int it = 0; it < 4; ++it) {
            const int m = it * 4 + q;
            const int s = __shfl(src_l, m);
            const float* bp = x_nbr + (size_t)s * 128 + n * 8;
            const float4 v0 = *(const float4*)bp;
            const float4 v1 = *(const float4*)(bp + 4);
            u32x4 pkv;
            pkv[0] = pk2(v0.x, v0.y); pkv[1] = pk2(v0.z, v0.w);
            pkv[2] = pk2(v1.x, v1.y); pkv[3] = pk2(v1.z, v1.w);
            Abuf[wid].v[m * 17 + n] = pkv;
        }
        // layer 1: K=128
        f32x4 acc[8];
#pragma unroll
        for (int nt = 0; nt < 8; ++nt) acc[nt] = zero;
#pragma unroll
        for (int kk = 0; kk < 4; ++kk) {
            const u32x4 a = Abuf[wid].v[n * 17 + kk * 4 + q];
#pragma unroll
            for (int nt = 0; nt < 8; ++nt)
                acc[nt] = __builtin_amdgcn_mfma_f32_16x16x32_bf16(
                    __builtin_bit_cast(bf16x8, a),
                    __builtin_bit_cast(bf16x8, wf[nt][kk]), acc[nt], 0, 0, 0);
        }
        // epilogue: + proj[dst], relu, write hidden tile (bf16)
        int dmr[4];
#pragma unroll
        for (int r = 0; r < 4; ++r) dmr[r] = __shfl(dst_l, q * 4 + r);
#pragma unroll
        for (int nt = 0; nt < 8; ++nt) {
#pragma unroll
            for (int r = 0; r < 4; ++r) {
                const float pv = bf2f(proj[(size_t)dmr[r] * 128 + nt * 16 + n]);
                float hv = acc[nt][r] + pv;
                hv = fmaxf(hv, 0.f);
                Hbuf[wid].h[(q * 4 + r) * 136 + nt * 16 + n] = (u16)f2bf(hv);
            }
        }
        // layer 2: [16,128] x [128,8(->16)]
        f32x4 acc2 = zero;
#pragma unroll
        for (int kk = 0; kk < 4; ++kk) {
            const u32x4 a2 = Hbuf[wid].v[n * 17 + kk * 4 + q];
            acc2 = __builtin_amdgcn_mfma_f32_16x16x32_bf16(
                __builtin_bit_cast(bf16x8, a2),
                __builtin_bit_cast(bf16x8, w2f[kk]), acc2, 0, 0, 0);
        }
        // scatter: row m = q*4+r, col n (<8 valid)
#pragma unroll
        for (int r = 0; r < 4; ++r) {
            const int m  = q * 4 + r;
            const int d  = __shfl(dst_l, m);
            const int sl = __shfl(slot_l, m);
            if (n < 8) out[(size_t)d * 264 + sl * 8 + n] = acc2[r] + b2v;
        }
    }
}

// ---------------------------------------------------------------------------
// Kernel 3: own_score = x_agent . Wa + ba  -> out[a][256..263];
// also zero-fills out[a][128..255] (pad slots 16..31 never written by edges).
// ---------------------------------------------------------------------------
__global__ void own_score_kernel(const float* __restrict__ x_agent,
                                 const float* __restrict__ Wa,
                                 const float* __restrict__ ba,
                                 float* __restrict__ out, int n_agents)
{
    const int tid = blockIdx.x * blockDim.x + threadIdx.x;
    const int a = tid >> 3, o = tid & 7;
    if (a >= n_agents) return;
    float acc = ba[o];
    const float* xr = x_agent + (size_t)a * 128;
#pragma unroll 4
    for (int k = 0; k < 128; k += 4) {
        const float4 x = *(const float4*)(xr + k);
        acc += x.x * Wa[(k + 0) * 8 + o];
        acc += x.y * Wa[(k + 1) * 8 + o];
        acc += x.z * Wa[(k + 2) * 8 + o];
        acc += x.w * Wa[(k + 3) * 8 + o];
    }
    float* rowo = out + (size_t)a * 264;
    const float4 z = {0.f, 0.f, 0.f, 0.f};
    float4* zp = (float4*)(rowo + 128 + o * 16);
    zp[0] = z; zp[1] = z; zp[2] = z; zp[3] = z;
    rowo[256 + o] = acc;
}

extern "C" void kernel_launch(void* const* d_in, const int* in_sizes, int n_in,
                              void* d_out, int out_size, void* d_ws, size_t ws_size,
                              hipStream_t stream)
{
    const float* x_nbr   = (const float*)d_in[0];
    const float* x_agent = (const float*)d_in[1];
    const float* W1      = (const float*)d_in[2];
    const float* b1      = (const float*)d_in[3];
    const float* W2      = (const float*)d_in[4];
    const float* b2      = (const float*)d_in[5];
    const float* Wa      = (const float*)d_in[6];
    const float* ba      = (const float*)d_in[7];
    const int* edge_src  = (const int*)d_in[8];
    const int* edge_dst  = (const int*)d_in[9];
    const int* edge_slot = (const int*)d_in[10];

    const int E        = in_sizes[8];
    const int n_agents = in_sizes[1] / 128;
    const int n_tiles  = E / 16;

    u16* proj = (u16*)d_ws;   // n_agents*128 bf16 = 12.8 MB scratch

    agent_proj_kernel<<<dim3(128), dim3(256), 0, stream>>>(x_agent, W1, b1, proj, n_agents);
    edge_mlp_kernel<<<dim3(512), dim3(256), 0, stream>>>(x_nbr, W1, W2, b2, proj,
                                                         edge_src, edge_dst, edge_slot,
                                                         (float*)d_out, n_tiles);
    const int othreads = n_agents * 8;
    own_score_kernel<<<dim3((othreads + 255) / 256), dim3(256), 0, stream>>>(
        x_agent, Wa, ba, (float*)d_out, n_agents);
}